// Round 26
// baseline (63.286 us; speedup 1.0000x reference)
//
#include <hip/hip_runtime.h>
#include <hip/hip_bf16.h>

#define BATCH 65536
#define INF   64
#define OUTF  256
#define NMAT  15
#define RPB   256          // rows per block
#define LDSW  36           // 32 cols + 4 pad floats

typedef __bf16 bf16x8 __attribute__((ext_vector_type(8)));
typedef float  f32x4  __attribute__((ext_vector_type(4)));

__device__ __forceinline__ unsigned short f2bf(float f) {
    unsigned int u = __float_as_uint(f);
    unsigned int r = (u + 0x7FFFu + ((u >> 16) & 1u)) >> 16;
    return (unsigned short)r;
}

// Opaque weight load (cannot be rematerialized/sunk). Outputs arrive async:
// vmcnt(0) drain must follow immediately, at minimal register pressure.
__device__ __forceinline__ void wload(bf16x8& d, const void* p) {
    asm volatile("global_load_dwordx4 %0, %1, off" : "=v"(d) : "v"(p));
}

// ---------------------------------------------------------------------------
// Weight layout (swizzled): per (mat w, 16-col strip cs):
//   byte = ((w*16+cs)*2+s)*1024 + lane*16   (lane = g*16+l15; k = s*32+g*8+j)
// slot order: 0=d1t, 1=d1_0, 2=M0, 3=d1_1, 4=M1, 5=M2, 6=d1_2, 7=M3, 8=M4,
// 9=M5, 10=d1_3, 11=M6, 12=M7, 13=M8, 14=M9  (M_p = dn_w2[p]*dn_w1[p][None,:])
// ---------------------------------------------------------------------------
__global__ void build_weights(const float* __restrict__ d1t_w,
                              const float* __restrict__ d1_w,
                              const float* __restrict__ dn_w1,
                              const float* __restrict__ dn_w2,
                              unsigned short* __restrict__ wcs) {
    const int idx = blockIdx.x * 256 + threadIdx.x;   // one 16-B chunk
    if (idx >= NMAT * OUTF * INF / 8) return;
    const signed char kind[NMAT] = {0,1,2,1,2,2,1,2,2,2,1,2,2,2,2};
    const signed char sidx[NMAT] = {0,0,0,1,1,2,2,3,4,5,3,6,7,8,9};
    const int slot = idx >> 11, rem8 = idx & 2047;
    const int o = rem8 >> 3, cc = rem8 & 7;
    const int s = cc >> 2, g = cc & 3;
    const int i0 = cc * 8;
    const int cs = o >> 4, l = o & 15;
    const int k = kind[slot], si = sidx[slot];
    unsigned short o8[8];
#pragma unroll
    for (int j = 0; j < 8; ++j) {
        const int e = o * INF + i0 + j;
        float v;
        if (k == 0)      v = d1t_w[e];
        else if (k == 1) v = d1_w[si * OUTF * INF + e];
        else             v = dn_w2[si * OUTF * INF + e] * dn_w1[si * INF + i0 + j];
        o8[j] = f2bf(v);
    }
    char* dst = (char*)wcs + (((size_t)slot * 16 + cs) * 2 + s) * 1024 + g * 256 + l * 16;
    *(bf16x8*)dst = *(bf16x8*)o8;
}

// 3-role split (R15 geometry, now safe: asm wload can't be sunk) + batch-2
// y-register ILP + in-kernel x staging. 5 mats/role = 40 wgt VGPR; total
// live ~100 << 128 cap -> spill-free at 4-waves/SIMD regalloc.
// role0 {d1t, T3=d1_2*M3*M4*M5}; role1 {T1=d1_0*M0, T2=d1_1*M1*M2};
// role2 {T4=d1_3*M6*M7*M8*M9}. Block = 384 thr (2 strips x 3 roles).
__global__ __launch_bounds__(384, 4) void taylor_kernel(
    const float* __restrict__ x, const float* __restrict__ d0w,
    const unsigned short* __restrict__ wcs, float* __restrict__ out)
{
    __shared__ char  xsh[32768];              // 256 rows x 64 k, bf16 swizzled
    __shared__ float sbuf[2][3][32 * LDSW];   // 27.6 KB combine buffer

    const int lane  = threadIdx.x & 63;
    const int wv    = threadIdx.x >> 6;   // 0..5
    const int strip = (wv >= 3) ? 1 : 0;  // 0..1
    const int role  = wv - 3 * strip;     // 0..2
    const int l15   = lane & 15;
    const int g     = lane >> 4;
    // sharers of one row-chunk: bids {rc + 256k} -> all == rc mod 8 -> same XCD
    const int cg    = blockIdx.x >> 8;    // 32-col group (0..7)
    const int rc    = blockIdx.x & 255;   // row-chunk (256 rows)
    const int cs    = cg * 2 + strip;     // global 16-col strip id (0..15)

    // ---- weight prologue: 5 mats/role, asm wloads, drained immediately -----
    const int M0a[5] = {0, 6, 7, 8, 9};        // d1t, d1_2, M3, M4, M5
    const int M1a[5] = {1, 2, 3, 4, 5};        // d1_0, M0, d1_1, M1, M2
    const int M2a[5] = {10, 11, 12, 13, 14};   // d1_3, M6, M7, M8, M9
    bf16x8 b[5][2];
    const char* wb0 = (const char*)wcs + lane * 16;
#pragma unroll
    for (int i = 0; i < 5; ++i) {
        const int m = (role == 0) ? M0a[i] : (role == 1) ? M1a[i] : M2a[i];
        const char* wp = wb0 + (((size_t)m * 16 + cs) * 2) * 1024;
        wload(b[i][0], wp);
        wload(b[i][1], wp + 1024);
    }
    asm volatile("s_waitcnt vmcnt(0)" ::: "memory");  // minimal-pressure drain
    __builtin_amdgcn_sched_barrier(0);

    const size_t row0 = (size_t)rc * RPB;

    // ---- in-kernel x staging: coalesced fp32 -> bf16 -> swizzled LDS -------
    {
        const float* xsrc = x + row0 * INF;
#pragma unroll
        for (int j = 0; j < 6; ++j) {
            const int c = j * 384 + (int)threadIdx.x;   // 8-float chunk 0..2047
            if (c < 2048) {
                f32x4 v0 = *(const f32x4*)(xsrc + (size_t)c * 8);
                f32x4 v1 = *(const f32x4*)(xsrc + (size_t)c * 8 + 4);
                bf16x8 fr;
#pragma unroll
                for (int q = 0; q < 4; ++q) { fr[q] = (__bf16)v0[q]; fr[4 + q] = (__bf16)v1[q]; }
                const int row = c >> 3, cc = c & 7;
                const int ss = cc >> 2, gg = cc & 3;
                const int grp = row >> 4, r_ = row & 15;
                const int rx = r_ ^ ((ss * 4 + gg) & 7);
                *(bf16x8*)(xsh + grp * 2048 + ss * 1024 + gg * 256 + rx * 16) = fr;
            }
        }
    }

    __syncthreads();   // all waves see staged xsh

    const f32x4 d0v = *(const f32x4*)(d0w + cs * 16 + g * 4);
    const int x0off = (l15 ^ g) * 16;             // s=0: swz id g
    const int x1off = (l15 ^ (4 + g)) * 16;       // s=1: swz id 4+g

#pragma unroll
    for (int t = 0; t < 8; ++t) {
        // ---- x frags from LDS (XOR-matched addresses) ----------------------
        const char* pg0 = xsh + (t * 2) * 2048 + g * 256;
        const char* pg1 = pg0 + 2048;
        bf16x8 u00 = *(const bf16x8*)(pg0 + x0off);
        bf16x8 u01 = *(const bf16x8*)(pg0 + 1024 + x1off);
        bf16x8 u10 = *(const bf16x8*)(pg1 + x0off);
        bf16x8 u11 = *(const bf16x8*)(pg1 + 1024 + x1off);

        f32x4 res0, res1, tmp0, tmp1;
        f32x4 y0a, y0b, y1a, y1b;
        const f32x4 z = {0.f, 0.f, 0.f, 0.f};
        __builtin_amdgcn_s_setprio(1);
#define YM(bi, ya, yb, c0)                                                          \
        ya = __builtin_amdgcn_mfma_f32_16x16x32_bf16(b[bi][0], u00, c0, 0, 0, 0);   \
        yb = __builtin_amdgcn_mfma_f32_16x16x32_bf16(b[bi][0], u10, c0, 0, 0, 0);   \
        ya = __builtin_amdgcn_mfma_f32_16x16x32_bf16(b[bi][1], u01, ya, 0, 0, 0);   \
        yb = __builtin_amdgcn_mfma_f32_16x16x32_bf16(b[bi][1], u11, yb, 0, 0, 0);

        if (role == 0) {
            // d0 + d1t + T3(d1_2*M3*M4*M5)
            YM(0, y0a, y0b, d0v)                     // d1t (+d0)
            YM(1, y1a, y1b, z)                       // d1_2
            res0 = y0a;  res1 = y0b;
            tmp0 = y1a;  tmp1 = y1b;
            YM(2, y0a, y0b, z)                       // M3
            YM(3, y1a, y1b, z)                       // M4
            tmp0 *= y0a; tmp1 *= y0b;
            tmp0 *= y1a; tmp1 *= y1b;
            YM(4, y0a, y0b, z)                       // M5
            tmp0 *= y0a; tmp1 *= y0b;
            res0 += tmp0; res1 += tmp1;
        } else if (role == 1) {
            // T1(d1_0*M0) + T2(d1_1*M1*M2)
            YM(0, y0a, y0b, z)                       // d1_0
            YM(1, y1a, y1b, z)                       // M0
            res0 = y0a * y1a; res1 = y0b * y1b;
            YM(2, y0a, y0b, z)                       // d1_1
            YM(3, y1a, y1b, z)                       // M1
            tmp0 = y0a * y1a; tmp1 = y0b * y1b;
            YM(4, y0a, y0b, z)                       // M2
            tmp0 *= y0a; tmp1 *= y0b;
            res0 += tmp0; res1 += tmp1;
        } else {
            // T4(d1_3*M6*M7*M8*M9)
            YM(0, y0a, y0b, z)                       // d1_3
            YM(1, y1a, y1b, z)                       // M6
            tmp0 = y0a * y1a; tmp1 = y0b * y1b;
            YM(2, y0a, y0b, z)                       // M7
            YM(3, y1a, y1b, z)                       // M8
            tmp0 *= y0a; tmp1 *= y0b;
            tmp0 *= y1a; tmp1 *= y1b;
            YM(4, y0a, y0b, z)                       // M9
            tmp0 *= y0a; tmp1 *= y0b;
            res0 = tmp0; res1 = tmp1;
        }
#undef YM
        __builtin_amdgcn_s_setprio(0);

        // ---- partials -> LDS (strips write disjoint 16-col ranges) ---------
        float* sb = &sbuf[t & 1][role][0];
        const int colw = strip * 16 + g * 4;
        *(f32x4*)&sb[l15 * LDSW + colw]        = res0;
        *(f32x4*)&sb[(16 + l15) * LDSW + colw] = res1;
        // lgkm-only barrier: output stores stay in flight (proven R11/R14+).
        asm volatile("s_waitcnt lgkmcnt(0)\n\ts_barrier" ::: "memory");

        // ---- store: sum of 3 roles, nontemporal full 128-B lines -----------
        const int rr = threadIdx.x >> 3;          // 0..47, guard to 0..31
        if (rr < 32) {
            const int c4 = (threadIdx.x & 7) * 4; // 0..28
            const float* p0 = &sbuf[t & 1][0][0];
            const float* p1 = &sbuf[t & 1][1][0];
            const float* p2 = &sbuf[t & 1][2][0];
            f32x4 v = *(const f32x4*)&p0[rr * LDSW + c4];
            v = v + *(const f32x4*)&p1[rr * LDSW + c4];
            v = v + *(const f32x4*)&p2[rr * LDSW + c4];
            float* op = out + (row0 + (size_t)t * 32 + rr) * OUTF + cg * 32 + c4;
            __builtin_nontemporal_store(v, (f32x4*)op);
        }
    }
}

extern "C" void kernel_launch(void* const* d_in, const int* in_sizes, int n_in,
                              void* d_out, int out_size, void* d_ws, size_t ws_size,
                              hipStream_t stream) {
    const float* x    = (const float*)d_in[0];
    const float* d0   = (const float*)d_in[1];
    const float* d1t  = (const float*)d_in[2];
    const float* d1w  = (const float*)d_in[3];
    const float* dnw1 = (const float*)d_in[4];
    const float* dnw2 = (const float*)d_in[5];
    unsigned short* wcs = (unsigned short*)d_ws;   // 480 KiB swizzled weights
    float* out = (float*)d_out;

    build_weights<<<(NMAT * OUTF * INF / 8 + 255) / 256, 256, 0, stream>>>(
        d1t, d1w, dnw1, dnw2, wcs);
    taylor_kernel<<<8 * (BATCH / RPB), 384, 0, stream>>>(x, d0, wcs, out);
}

// Round 27
// 42.781 us; speedup vs baseline: 1.4793x; 1.4793x over previous
//
#include <hip/hip_runtime.h>
#include <hip/hip_bf16.h>

#define BATCH 65536
#define INF   64
#define OUTF  256
#define NMAT  15
#define RPB   256          // rows per block
#define LDSW  36           // 32 cols + 4 pad floats

typedef __bf16 bf16x8 __attribute__((ext_vector_type(8)));
typedef float  f32x4  __attribute__((ext_vector_type(4)));

__device__ __forceinline__ unsigned short f2bf(float f) {
    unsigned int u = __float_as_uint(f);
    unsigned int r = (u + 0x7FFFu + ((u >> 16) & 1u)) >> 16;
    return (unsigned short)r;
}

// Opaque weight load (cannot be rematerialized/sunk). Drained by vmcnt(0)
// IMMEDIATELY after the load batch, before any other VMEM (R24/R25 lesson).
__device__ __forceinline__ void wload(bf16x8& d, const void* p) {
    asm volatile("global_load_dwordx4 %0, %1, off" : "=v"(d) : "v"(p));
}

// ---------------------------------------------------------------------------
// Layouts (proven):
//   xs:  per 16-row group grp: byte = grp*2048 + s*1024 + lane*16
//        (lane = g*16 + r, r = row&15, k = s*32 + g*8 + j)
//   wcs: per (mat w, 16-col strip cs): byte = ((w*16+cs)*2+s)*1024 + lane*16
// ---------------------------------------------------------------------------
__global__ void prep(const float* __restrict__ x,
                     const float* __restrict__ d1t_w,
                     const float* __restrict__ d1_w,
                     const float* __restrict__ dn_w1,
                     const float* __restrict__ dn_w2,
                     unsigned short* __restrict__ wcs,
                     unsigned short* __restrict__ xs) {
    const int idx = blockIdx.x * 256 + threadIdx.x;   // one 16-B chunk each

    {   // x: chunk idx covers row = idx>>3, elems cc*8..cc*8+7
        const int row = idx >> 3, cc = idx & 7;
        const int s = cc >> 2, g = cc & 3;
        const int grp = row >> 4, r = row & 15;
        const float* xp = x + (size_t)row * INF + cc * 8;
        f32x4 v0 = *(const f32x4*)xp;
        f32x4 v1 = *(const f32x4*)(xp + 4);
        bf16x8 fr;
#pragma unroll
        for (int j = 0; j < 4; ++j) { fr[j] = (__bf16)v0[j]; fr[4 + j] = (__bf16)v1[j]; }
        *(bf16x8*)((char*)xs + (size_t)grp * 2048 + s * 1024 + g * 256 + r * 16) = fr;
    }

    if (idx < NMAT * OUTF * INF / 8) {
        const signed char kind[NMAT] = {0,1,2,1,2,2,1,2,2,2,1,2,2,2,2};
        const signed char sidx[NMAT] = {0,0,0,1,1,2,2,3,4,5,3,6,7,8,9};
        const int slot = idx >> 11, rem8 = idx & 2047;
        const int o = rem8 >> 3, cc = rem8 & 7;
        const int s = cc >> 2, g = cc & 3;
        const int i0 = cc * 8;
        const int cs = o >> 4, l = o & 15;
        const int k = kind[slot], si = sidx[slot];
        unsigned short o8[8];
#pragma unroll
        for (int j = 0; j < 8; ++j) {
            const int e = o * INF + i0 + j;
            float v;
            if (k == 0)      v = d1t_w[e];
            else if (k == 1) v = d1_w[si * OUTF * INF + e];
            else             v = dn_w2[si * OUTF * INF + e] * dn_w1[si * INF + i0 + j];
            o8[j] = f2bf(v);
        }
        char* dst = (char*)wcs + (((size_t)slot * 16 + cs) * 2 + s) * 1024 + g * 256 + l * 16;
        *(bf16x8*)dst = *(bf16x8*)o8;
    }
}

// R20 structure (2-role A/B, 256-thr blocks, (256,3) -> 168-reg headroom,
// NT full-line stores) + BATCH-2 y-register ILP: 8 MFMAs issue back-to-back
// per batch (4 independent chains), combine VALU runs after, serialization
// points per tile drop 15 -> 4 per role. Live regs ~138 < 168: spill-free.
__global__ __launch_bounds__(256, 3) void taylor_kernel(
    const unsigned short* __restrict__ xs, const float* __restrict__ d0w,
    const unsigned short* __restrict__ wcs, float* __restrict__ out)
{
    __shared__ float sbuf[2][2][32 * LDSW];   // 18 KB

    const int lane  = threadIdx.x & 63;
    const int wv    = threadIdx.x >> 6;   // 0..3
    const int strip = wv >> 1;            // 0..1
    const int role  = wv & 1;             // 0=A, 1=B
    const int l15   = lane & 15;
    const int g     = lane >> 4;
    // sharers of one row-chunk: bids {rc + 256k} -> all == rc mod 8 -> same XCD
    const int cg    = blockIdx.x >> 8;    // 32-col group (0..7)
    const int rc    = blockIdx.x & 255;   // row-chunk (256 rows)
    const int cs    = cg * 2 + strip;     // global 16-col strip id (0..15)

    // ---- weight prologue: asm wloads, drained before any other VMEM --------
    // A: b[0]=d1t b[1]=d1_0 b[2]=M0 b[3]=d1_2 b[4]=M3 b[5]=M4 b[6]=M5
    // B: b[0]=d1_1 b[1]=M1 b[2]=M2 b[3]=d1_3 b[4]=M6 b[5]=M7 b[6]=M8 b[7]=M9
    const int MA[8] = {0, 1, 2, 6, 7, 8, 9, 9};
    const int MB[8] = {3, 4, 5, 10, 11, 12, 13, 14};
    bf16x8 b[8][2];
    const char* wb0 = (const char*)wcs + lane * 16;
#pragma unroll
    for (int i = 0; i < 8; ++i) {
        const int m = role ? MB[i] : MA[i];
        if (role == 0 && i == 7) continue;            // A: only 7 mats
        const char* wp = wb0 + (((size_t)m * 16 + cs) * 2) * 1024;
        wload(b[i][0], wp);
        wload(b[i][1], wp + 1024);
    }
    asm volatile("s_waitcnt vmcnt(0)" ::: "memory");  // only wloads outstanding
    __builtin_amdgcn_sched_barrier(0);

    const f32x4 d0v = *(const f32x4*)(d0w + cs * 16 + g * 4);
    const size_t row0 = (size_t)rc * RPB;
    const char* xbase = (const char*)xs + (row0 >> 4) * 2048 + lane * 16;

    // prologue: tile 0
    bf16x8 u00 = *(const bf16x8*)(xbase);
    bf16x8 u01 = *(const bf16x8*)(xbase + 1024);
    bf16x8 u10 = *(const bf16x8*)(xbase + 2048);
    bf16x8 u11 = *(const bf16x8*)(xbase + 3072);

#pragma unroll
    for (int t = 0; t < 8; ++t) {
        f32x4 res0, res1, tmp0, tmp1;
        f32x4 y0a, y0b, y1a, y1b;
        const f32x4 z = {0.f, 0.f, 0.f, 0.f};
        __builtin_amdgcn_s_setprio(1);
#define YM(bi, ya, yb, c0)                                                          \
        ya = __builtin_amdgcn_mfma_f32_16x16x32_bf16(b[bi][0], u00, c0, 0, 0, 0);   \
        yb = __builtin_amdgcn_mfma_f32_16x16x32_bf16(b[bi][0], u10, c0, 0, 0, 0);   \
        ya = __builtin_amdgcn_mfma_f32_16x16x32_bf16(b[bi][1], u01, ya, 0, 0, 0);   \
        yb = __builtin_amdgcn_mfma_f32_16x16x32_bf16(b[bi][1], u11, yb, 0, 0, 0);

        if (role == 0) {
            // A: d0 + d1t + T1(d1_0*M0) + T3(d1_2*M3*M4*M5)
            YM(0, y0a, y0b, d0v)                     // d1t (+d0)
            YM(1, y1a, y1b, z)                       // d1_0
            res0 = y0a;  res1 = y0b;
            tmp0 = y1a;  tmp1 = y1b;
            YM(2, y0a, y0b, z)                       // M0
            YM(3, y1a, y1b, z)                       // d1_2
            tmp0 *= y0a; tmp1 *= y0b; res0 += tmp0; res1 += tmp1;
            tmp0 = y1a;  tmp1 = y1b;
            YM(4, y0a, y0b, z)                       // M3
            YM(5, y1a, y1b, z)                       // M4
            tmp0 *= y0a; tmp1 *= y0b;
            tmp0 *= y1a; tmp1 *= y1b;
            YM(6, y0a, y0b, z)                       // M5
            tmp0 *= y0a; tmp1 *= y0b; res0 += tmp0; res1 += tmp1;
        } else {
            // B: T2(d1_1*M1*M2) + T4(d1_3*M6*M7*M8*M9)
            YM(0, y0a, y0b, z)                       // d1_1
            YM(1, y1a, y1b, z)                       // M1
            tmp0 = y0a * y1a;  tmp1 = y0b * y1b;
            YM(2, y0a, y0b, z)                       // M2
            YM(3, y1a, y1b, z)                       // d1_3
            res0 = tmp0 * y0a; res1 = tmp1 * y0b;
            tmp0 = y1a;        tmp1 = y1b;
            YM(4, y0a, y0b, z)                       // M6
            YM(5, y1a, y1b, z)                       // M7
            tmp0 *= y0a; tmp1 *= y0b;
            tmp0 *= y1a; tmp1 *= y1b;
            YM(6, y0a, y0b, z)                       // M8
            YM(7, y1a, y1b, z)                       // M9
            tmp0 *= y0a; tmp1 *= y0b;
            tmp0 *= y1a; tmp1 *= y1b;
            res0 += tmp0; res1 += tmp1;
        }
#undef YM
        __builtin_amdgcn_s_setprio(0);

        // ---- pipelined load of tile t+1 into the same regs (WAR-ordered) ---
        if (t < 7) {
            const char* p = xbase + (size_t)(t + 1) * 4096;
            u00 = *(const bf16x8*)(p);
            u01 = *(const bf16x8*)(p + 1024);
            u10 = *(const bf16x8*)(p + 2048);
            u11 = *(const bf16x8*)(p + 3072);
        }

        // ---- partials -> LDS -----------------------------------------------
        float* sb = &sbuf[t & 1][role][0];
        const int colw = strip * 16 + g * 4;
        *(f32x4*)&sb[l15 * LDSW + colw]        = res0;
        *(f32x4*)&sb[(16 + l15) * LDSW + colw] = res1;
        // lgkm-only barrier: VMEM stays in flight (proven R11/R14/R16/R19).
        asm volatile("s_waitcnt lgkmcnt(0)\n\ts_barrier" ::: "memory");

        // ---- store: A+B, nontemporal full 128-B lines ----------------------
        const float* pA = &sbuf[t & 1][0][0];
        const float* pB = &sbuf[t & 1][1][0];
        const int rr = threadIdx.x >> 3;          // 0..31
        const int c4 = (threadIdx.x & 7) * 4;     // 0..28
        f32x4 v = *(const f32x4*)&pA[rr * LDSW + c4];
        v = v + *(const f32x4*)&pB[rr * LDSW + c4];
        float* op = out + (row0 + (size_t)t * 32 + rr) * OUTF + cg * 32 + c4;
        __builtin_nontemporal_store(v, (f32x4*)op);
    }
}

extern "C" void kernel_launch(void* const* d_in, const int* in_sizes, int n_in,
                              void* d_out, int out_size, void* d_ws, size_t ws_size,
                              hipStream_t stream) {
    const float* x    = (const float*)d_in[0];
    const float* d0   = (const float*)d_in[1];
    const float* d1t  = (const float*)d_in[2];
    const float* d1w  = (const float*)d_in[3];
    const float* dnw1 = (const float*)d_in[4];
    const float* dnw2 = (const float*)d_in[5];
    unsigned short* wcs = (unsigned short*)d_ws;                // 480 KiB
    float* out = (float*)d_out;

    unsigned short* xsb = (unsigned short*)((char*)d_ws + 512 * 1024);  // 8 MiB
    prep<<<BATCH * INF / 8 / 256, 256, 0, stream>>>(x, d1t, d1w, dnw1, dnw2, wcs, xsb);
    taylor_kernel<<<8 * (BATCH / RPB), 256, 0, stream>>>(xsb, d0, wcs, out);
}

// Round 28
// 41.212 us; speedup vs baseline: 1.5356x; 1.0381x over previous
//
#include <hip/hip_runtime.h>
#include <hip/hip_bf16.h>

#define BATCH 65536
#define INF   64
#define OUTF  256
#define NMAT  15
#define RPB   256          // rows per block
#define LDSW  68           // 64 cols + 4 pad floats

typedef __bf16 bf16x8 __attribute__((ext_vector_type(8)));
typedef float  f32x4  __attribute__((ext_vector_type(4)));

__device__ __forceinline__ unsigned short f2bf(float f) {
    unsigned int u = __float_as_uint(f);
    unsigned int r = (u + 0x7FFFu + ((u >> 16) & 1u)) >> 16;
    return (unsigned short)r;
}

// Opaque weight load: asm-produced value cannot be rematerialized/sunk
// (residency guaranteed; mechanism verified R21 via FETCH drop).
__device__ __forceinline__ void wload(bf16x8& d, const void* p) {
    asm volatile("global_load_dwordx4 %0, %1, off" : "=v"(d) : "v"(p));
}

// ---------------------------------------------------------------------------
// Weight layout (swizzled): per (mat w, 16-col strip cs):
//   byte = ((w*16+cs)*2+s)*1024 + lane*16   (lane = g*16+l15; k = s*32+g*8+j)
// slot order: 0=d1t, 1=d1_0, 2=M0, 3=d1_1, 4=M1, 5=M2, 6=d1_2, 7=M3, 8=M4,
// 9=M5, 10=d1_3, 11=M6, 12=M7, 13=M8, 14=M9  (M_p = dn_w2[p]*dn_w1[p][None,:])
// ---------------------------------------------------------------------------
__global__ void build_weights(const float* __restrict__ d1t_w,
                              const float* __restrict__ d1_w,
                              const float* __restrict__ dn_w1,
                              const float* __restrict__ dn_w2,
                              unsigned short* __restrict__ wcs) {
    const int idx = blockIdx.x * 256 + threadIdx.x;   // one 16-B chunk
    if (idx >= NMAT * OUTF * INF / 8) return;
    const signed char kind[NMAT] = {0,1,2,1,2,2,1,2,2,2,1,2,2,2,2};
    const signed char sidx[NMAT] = {0,0,0,1,1,2,2,3,4,5,3,6,7,8,9};
    const int slot = idx >> 11, rem8 = idx & 2047;
    const int o = rem8 >> 3, cc = rem8 & 7;
    const int s = cc >> 2, g = cc & 3;
    const int i0 = cc * 8;
    const int cs = o >> 4, l = o & 15;
    const int k = kind[slot], si = sidx[slot];
    unsigned short o8[8];
#pragma unroll
    for (int j = 0; j < 8; ++j) {
        const int e = o * INF + i0 + j;
        float v;
        if (k == 0)      v = d1t_w[e];
        else if (k == 1) v = d1_w[si * OUTF * INF + e];
        else             v = dn_w2[si * OUTF * INF + e] * dn_w1[si * INF + i0 + j];
        o8[j] = f2bf(v);
    }
    char* dst = (char*)wcs + (((size_t)slot * 16 + cs) * 2 + s) * 1024 + g * 256 + l * 16;
    *(bf16x8*)dst = *(bf16x8*)o8;
}

// Best-measured kernel (R23, 40.8 us total): in-kernel x staging (coalesced
// fp32 -> bf16 -> XOR-swizzled LDS), asm-pinned weights, role-split A/B,
// lgkm-only barrier, NT 256-B row-segment stores.
__global__ __launch_bounds__(512, 4) void taylor_kernel(
    const float* __restrict__ x, const float* __restrict__ d0w,
    const unsigned short* __restrict__ wcs, float* __restrict__ out)
{
    __shared__ char  xsh[32768];              // 256 rows x 64 k, bf16 swizzled
    __shared__ float sbuf[2][2][32 * LDSW];   // 34.8 KB combine buffer

    const int lane  = threadIdx.x & 63;
    const int wv    = threadIdx.x >> 6;   // 0..7
    const int strip = wv >> 1;            // 0..3
    const int role  = wv & 1;             // 0=A, 1=B
    const int l15   = lane & 15;
    const int g     = lane >> 4;
    // sharers of one row-chunk: bids {rc + 256k, k=0..3} -> all == rc mod 8
    const int cg    = blockIdx.x >> 8;    // 64-col group (0..3)
    const int rc    = blockIdx.x & 255;   // row-chunk (256 rows)
    const int cs    = cg * 4 + strip;     // global 16-col strip id (0..15)

    // ---- weight prologue: opaque asm loads (residency-guaranteed) ----------
    const int MA[8] = {0, 1, 2, 6, 7, 8, 9, 9};       // A uses first 7
    const int MB[8] = {3, 4, 5, 10, 11, 12, 13, 14};  // B uses all 8
    bf16x8 b[8][2];
    const char* wb0 = (const char*)wcs + lane * 16;
#pragma unroll
    for (int i = 0; i < 8; ++i) {
        const int m = role ? MB[i] : MA[i];
        if (role == 0 && i == 7) continue;            // A: only 7 mats
        const char* wp = wb0 + (((size_t)m * 16 + cs) * 2) * 1024;
        wload(b[i][0], wp);
        wload(b[i][1], wp + 1024);
    }

    const size_t row0 = (size_t)rc * RPB;

    // ---- in-kernel x staging: coalesced fp32 -> bf16 -> swizzled LDS -------
    {
        const float* xsrc = x + row0 * INF;
#pragma unroll
        for (int j = 0; j < 4; ++j) {
            const int c = j * 512 + (int)threadIdx.x;   // 8-float chunk 0..2047
            f32x4 v0 = *(const f32x4*)(xsrc + (size_t)c * 8);
            f32x4 v1 = *(const f32x4*)(xsrc + (size_t)c * 8 + 4);
            bf16x8 fr;
#pragma unroll
            for (int q = 0; q < 4; ++q) { fr[q] = (__bf16)v0[q]; fr[4 + q] = (__bf16)v1[q]; }
            const int row = c >> 3, cc = c & 7;
            const int ss = cc >> 2, gg = cc & 3;
            const int grp = row >> 4, r_ = row & 15;
            const int rx = r_ ^ ((ss * 4 + gg) & 7);
            *(bf16x8*)(xsh + grp * 2048 + ss * 1024 + gg * 256 + rx * 16) = fr;
        }
    }

    // drain weight wloads (rule #18: keep MFMAs below), then full barrier so
    // every wave sees the staged xsh.
    asm volatile("s_waitcnt vmcnt(0)" ::: "memory");
    __builtin_amdgcn_sched_barrier(0);
    __syncthreads();

    const f32x4 d0v = *(const f32x4*)(d0w + cs * 16 + g * 4);
    const int x0off = (l15 ^ g) * 16;             // s=0: (0*4+g)&7 = g
    const int x1off = (l15 ^ (4 + g)) * 16;       // s=1: (4+g)&7 = 4+g

#pragma unroll
    for (int t = 0; t < 8; ++t) {
        // ---- x frags from LDS (XOR-matched addresses) ----------------------
        const char* pg0 = xsh + (t * 2) * 2048 + g * 256;
        const char* pg1 = pg0 + 2048;
        bf16x8 u00 = *(const bf16x8*)(pg0 + x0off);
        bf16x8 u01 = *(const bf16x8*)(pg0 + 1024 + x1off);
        bf16x8 u10 = *(const bf16x8*)(pg1 + x0off);
        bf16x8 u11 = *(const bf16x8*)(pg1 + 1024 + x1off);

        f32x4 res0, res1, tmp0, tmp1, y0, y1;
        const f32x4 z = {0.f, 0.f, 0.f, 0.f};
        __builtin_amdgcn_s_setprio(1);
#define Y4(bi, c0)                                                                  \
        y0 = __builtin_amdgcn_mfma_f32_16x16x32_bf16(b[bi][0], u00, c0, 0, 0, 0);   \
        y1 = __builtin_amdgcn_mfma_f32_16x16x32_bf16(b[bi][0], u10, c0, 0, 0, 0);   \
        y0 = __builtin_amdgcn_mfma_f32_16x16x32_bf16(b[bi][1], u01, y0, 0, 0, 0);   \
        y1 = __builtin_amdgcn_mfma_f32_16x16x32_bf16(b[bi][1], u11, y1, 0, 0, 0);
        if (role == 0) {
            Y4(0, d0v) res0 = y0; res1 = y1;                      // d1t (+d0)
            Y4(1, z)   tmp0 = y0; tmp1 = y1;                      // T1
            Y4(2, z)   tmp0 *= y0; tmp1 *= y1; res0 += tmp0; res1 += tmp1;
            Y4(3, z)   tmp0 = y0; tmp1 = y1;                      // T3
            Y4(4, z)   tmp0 *= y0; tmp1 *= y1;
            Y4(5, z)   tmp0 *= y0; tmp1 *= y1;
            Y4(6, z)   tmp0 *= y0; tmp1 *= y1; res0 += tmp0; res1 += tmp1;
        } else {
            Y4(0, z)   tmp0 = y0; tmp1 = y1;                      // T2
            Y4(1, z)   tmp0 *= y0; tmp1 *= y1;
            Y4(2, z)   tmp0 *= y0; tmp1 *= y1; res0 = tmp0; res1 = tmp1;
            Y4(3, z)   tmp0 = y0; tmp1 = y1;                      // T4
            Y4(4, z)   tmp0 *= y0; tmp1 *= y1;
            Y4(5, z)   tmp0 *= y0; tmp1 *= y1;
            Y4(6, z)   tmp0 *= y0; tmp1 *= y1;
            Y4(7, z)   tmp0 *= y0; tmp1 *= y1; res0 += tmp0; res1 += tmp1;
        }
#undef Y4
        __builtin_amdgcn_s_setprio(0);

        // ---- partials -> LDS (strips write disjoint 16-col ranges) ---------
        float* sb = &sbuf[t & 1][role][0];
        const int colw = strip * 16 + g * 4;
        *(f32x4*)&sb[l15 * LDSW + colw]        = res0;
        *(f32x4*)&sb[(16 + l15) * LDSW + colw] = res1;
        // lgkm-only barrier: output stores stay in flight (proven R11/R14+).
        asm volatile("s_waitcnt lgkmcnt(0)\n\ts_barrier" ::: "memory");

        // ---- store: A+B, nontemporal 256-B row segments --------------------
        const float* pA = &sbuf[t & 1][0][0];
        const float* pB = &sbuf[t & 1][1][0];
        const int rr = threadIdx.x >> 4;          // 0..31
        const int c4 = (threadIdx.x & 15) * 4;    // 0..60
        f32x4 v = *(const f32x4*)&pA[rr * LDSW + c4];
        v = v + *(const f32x4*)&pB[rr * LDSW + c4];
        float* op = out + (row0 + (size_t)t * 32 + rr) * OUTF + cg * 64 + c4;
        __builtin_nontemporal_store(v, (f32x4*)op);
    }
}

extern "C" void kernel_launch(void* const* d_in, const int* in_sizes, int n_in,
                              void* d_out, int out_size, void* d_ws, size_t ws_size,
                              hipStream_t stream) {
    const float* x    = (const float*)d_in[0];
    const float* d0   = (const float*)d_in[1];
    const float* d1t  = (const float*)d_in[2];
    const float* d1w  = (const float*)d_in[3];
    const float* dnw1 = (const float*)d_in[4];
    const float* dnw2 = (const float*)d_in[5];
    unsigned short* wcs = (unsigned short*)d_ws;   // 480 KiB swizzled weights
    float* out = (float*)d_out;

    build_weights<<<(NMAT * OUTF * INF / 8 + 255) / 256, 256, 0, stream>>>(
        d1t, d1w, dnw1, dnw2, wcs);
    taylor_kernel<<<4 * (BATCH / RPB), 512, 0, stream>>>(x, d0, wcs, out);
}